// Round 4
// baseline (339.828 us; speedup 1.0000x reference)
//
#include <hip/hip_runtime.h>

#define BB 8
#define HH 256
#define WW 512
#define HW (HH * WW)          // 131072
#define NPIX (BB * HW)        // 1048576

#define TXI 64                // inner tile width
#define TYI 32                // inner tile height
#define HALO 4                // = iterations fused per kernel
#define SX (TXI + 2 * HALO)   // 72 staged width
#define SY (TYI + 2 * HALO)   // 40 staged height
#define NST (SX * SY)         // 2880 staged pixels
#define CW 70                 // computed width  (SX-2)
#define CHMAX (SY - 2)        // last computed row index = 38
#define THR 320               // 5 waves; 280 active compute threads (70 cols x 4 grps)
#define RPT 10                // max rows per thread

typedef _Float16 half8 __attribute__((ext_vector_type(8)));

// ---------------------------------------------------------------- prep ----
__global__ __launch_bounds__(256) void prep_kernel(
    const float* __restrict__ guidance,   // [B,8,H,W] NCHW fp32
    const float* __restrict__ blur,
    const float* __restrict__ sparse,
    half8* __restrict__ g_cl,             // [B,H,W,8] fp16
    float* __restrict__ d0)
{
    const int idx = blockIdx.x * 256 + threadIdx.x;
    const int b = idx >> 17;
    const int p = idx & (HW - 1);
    const size_t gbase = ((size_t)b * 8) * HW + p;

    half8 h;
#pragma unroll
    for (int c = 0; c < 8; ++c)
        h[c] = (_Float16)fabsf(guidance[gbase + (size_t)c * HW]);
    g_cl[idx] = h;

    const float sp = sparse[idx];
    d0[idx] = (sp > 0.0f) ? sp : blur[idx];
}

// ---------------------------------------------------------------- wsum ----
__global__ __launch_bounds__(256) void wsum_kernel(
    const half8* __restrict__ g_cl,
    half8* __restrict__ invw)
{
    const int x = blockIdx.x * 64 + threadIdx.x;
    const int y = blockIdx.y * 4 + threadIdx.y;
    const int b = blockIdx.z;
    const int p = (b * HH + y) * WW + x;

    float s[8];
#pragma unroll
    for (int i = 0; i < 8; ++i) s[i] = 0.0f;

#pragma unroll
    for (int dy = -1; dy <= 1; ++dy) {
        const int yy = y + dy;
        if ((unsigned)yy >= HH) continue;
#pragma unroll
        for (int dx = -1; dx <= 1; ++dx) {
            const int xx = x + dx;
            if ((unsigned)xx >= WW) continue;
            const half8 gh = g_cl[(b * HH + yy) * WW + xx];
#pragma unroll
            for (int c = 0; c < 8; ++c) s[c] += (float)gh[c];
        }
    }

    half8 w;
#pragma unroll
    for (int c = 0; c < 8; ++c) w[c] = (_Float16)(1.0f / s[c]);
    invw[p] = w;
}

// --------------------------------------------------------------- fused ----
// 4 diffusion iterations in LDS. Staged 72x40 (tile + halo 4); outermost
// ring frozen at input d; computed region 70x38; inner 64x32 exact after 4.
__global__ __launch_bounds__(THR) void fused_kernel(
    const half8* __restrict__ g_cl,       // [B,H,W,8] fp16
    const half8* __restrict__ invw,       // [B,H,W,8] fp16
    const float* __restrict__ sparse,     // [B,H,W]
    const float* __restrict__ src,        // [B,H,W] d in
    float* __restrict__ dst)              // [B,H,W] d out
{
    __shared__ _Float16 g_lds[SY][SX][8];   // 46080 B
    __shared__ float    d_lds[SY][SX];      // 11520 B

    const int t  = threadIdx.x;
    const int b  = blockIdx.z;
    const int X0 = blockIdx.x * TXI;
    const int Y0 = blockIdx.y * TYI;

    // ---- stage g (fp16 CL) and d into LDS, zero outside image ----
    for (int idx = t; idx < NST; idx += THR) {
        const int sy = idx / SX;
        const int sx = idx - sy * SX;
        const int gy = Y0 - HALO + sy;
        const int gx = X0 - HALO + sx;
        half8 h;
#pragma unroll
        for (int c = 0; c < 8; ++c) h[c] = (_Float16)0.0f;
        float dv = 0.0f;
        if ((unsigned)gy < HH && (unsigned)gx < WW) {
            const size_t q = ((size_t)b * HH + gy) * WW + gx;
            h  = g_cl[q];
            dv = src[q];
        }
        *(half8*)&g_lds[sy][sx][0] = h;
        d_lds[sy][sx] = dv;
    }

    // ---- per-thread fixed pixel set: column sxc, rows syB..syB+9 ----
    const int col = t % CW;              // 0..69
    const int grp = t / CW;              // 0..3 compute, 4 = idle
    const int sxc = 1 + col;             // staged x (computed cols 1..70)
    const int syB = 1 + grp * RPT;       // first computed staged row

    half8 winv[RPT];
    float spv[RPT];
    float dnew[RPT];
    bool  valid[RPT];
#pragma unroll
    for (int k = 0; k < RPT; ++k) {
        const int sy = syB + k;
        const int gy = Y0 - HALO + sy;
        const int gx = X0 - HALO + sxc;
        const bool v = (grp < 4) && (sy <= CHMAX) &&
                       ((unsigned)gy < HH) && ((unsigned)gx < WW);
        valid[k] = v;
        if (v) {
            const size_t q = ((size_t)b * HH + gy) * WW + gx;
            winv[k] = invw[q];
            spv[k]  = sparse[q];
        } else {
#pragma unroll
            for (int c = 0; c < 8; ++c) winv[k][c] = (_Float16)0.0f;
            spv[k] = 0.0f;
        }
        dnew[k] = 0.0f;
    }
    __syncthreads();

    // ---- 4 in-LDS iterations ----
    for (int it = 0; it < HALO; ++it) {
        float rs[3][8];
        // rolling row-sums: row r -> sum_dx g[r][sxc+dx]*d[r][sxc+dx]
        {
            const int r0 = syB - 1;               // >= 0
#pragma unroll
            for (int c = 0; c < 8; ++c) { rs[0][c] = 0.0f; rs[1][c] = 0.0f; }
#pragma unroll
            for (int dx = 0; dx < 3; ++dx) {
                const half8 ga = *(const half8*)&g_lds[r0][sxc - 1 + dx][0];
                const float da = d_lds[r0][sxc - 1 + dx];
                const int r1 = (syB < SY) ? syB : (SY - 1);
                const half8 gb = *(const half8*)&g_lds[r1][sxc - 1 + dx][0];
                const float db = d_lds[r1][sxc - 1 + dx];
#pragma unroll
                for (int c = 0; c < 8; ++c) {
                    rs[0][c] = fmaf((float)ga[c], da, rs[0][c]);
                    rs[1][c] = fmaf((float)gb[c], db, rs[1][c]);
                }
            }
        }
#pragma unroll
        for (int k = 0; k < RPT; ++k) {
            const int rn = syB + 1 + k;
            const int rc = (rn < SY) ? rn : (SY - 1);   // clamp (values unused)
            float* rsn = rs[(2 + k) % 3];
#pragma unroll
            for (int c = 0; c < 8; ++c) rsn[c] = 0.0f;
#pragma unroll
            for (int dx = 0; dx < 3; ++dx) {
                const half8 gh = *(const half8*)&g_lds[rc][sxc - 1 + dx][0];
                const float dv = d_lds[rc][sxc - 1 + dx];
#pragma unroll
                for (int c = 0; c < 8; ++c)
                    rsn[c] = fmaf((float)gh[c], dv, rsn[c]);
            }
            const int ia = k % 3, ib = (k + 1) % 3, ic = (k + 2) % 3;
            float m = 0.0f;                      // all candidates >= 0
            const half8 w = winv[k];
#pragma unroll
            for (int c = 0; c < 8; ++c) {
                const float s = rs[ia][c] + rs[ib][c] + rs[ic][c];
                m = fmaxf(m, s * (float)w[c]);
            }
            dnew[k] = (spv[k] > 0.0f) ? spv[k] : m;
        }
        __syncthreads();                         // all reads done
#pragma unroll
        for (int k = 0; k < RPT; ++k)
            if (valid[k]) d_lds[syB + k][sxc] = dnew[k];
        __syncthreads();                         // all writes visible
    }

    // ---- write inner tile ----
#pragma unroll
    for (int k = 0; k < RPT; ++k) {
        const int sy = syB + k;
        if (valid[k] && sxc >= HALO && sxc < HALO + TXI &&
            sy >= HALO && sy < HALO + TYI) {
            const int gy = Y0 - HALO + sy;
            const int gx = X0 - HALO + sxc;
            dst[((size_t)b * HH + gy) * WW + gx] = dnew[k];
        }
    }
}

// -------------------------------------------------------------- launch ----
extern "C" void kernel_launch(void* const* d_in, const int* in_sizes, int n_in,
                              void* d_out, int out_size, void* d_ws, size_t ws_size,
                              hipStream_t stream) {
    const float* guidance = (const float*)d_in[0];
    const float* blur     = (const float*)d_in[1];
    const float* sparse   = (const float*)d_in[2];
    float* out = (float*)d_out;

    half8* g_cl  = (half8*)d_ws;                          // 16.78 MB
    half8* invw  = g_cl + (size_t)NPIX;                   // 16.78 MB
    float* buf0  = (float*)(invw + (size_t)NPIX);         // 4 MB
    float* buf1  = buf0 + (size_t)NPIX;                   // 4 MB

    prep_kernel<<<NPIX / 256, 256, 0, stream>>>(guidance, blur, sparse, g_cl, buf0);

    dim3 blkw(64, 4, 1);
    dim3 grdw(WW / 64, HH / 4, BB);
    wsum_kernel<<<grdw, blkw, 0, stream>>>(g_cl, invw);

    dim3 grdf(WW / TXI, HH / TYI, BB);   // 8 x 8 x 8 = 512 blocks
    fused_kernel<<<grdf, THR, 0, stream>>>(g_cl, invw, sparse, buf0, buf1);
    fused_kernel<<<grdf, THR, 0, stream>>>(g_cl, invw, sparse, buf1, buf0);
    fused_kernel<<<grdf, THR, 0, stream>>>(g_cl, invw, sparse, buf0, buf1);
    fused_kernel<<<grdf, THR, 0, stream>>>(g_cl, invw, sparse, buf1, out);
}